// Round 4
// baseline (3109.106 us; speedup 1.0000x reference)
//
#include <hip/hip_runtime.h>
#include <hip/hip_bf16.h>
#include <math.h>

typedef __bf16 bf16x8 __attribute__((ext_vector_type(8)));
typedef float f32x4 __attribute__((ext_vector_type(4)));

#define MFMA16(a,b,c) __builtin_amdgcn_mfma_f32_16x16x32_bf16(a,b,c,0,0,0)

constexpr int BATCH = 1024, SEQ = 80, EMB = 100, U = 512;
constexpr int K1 = 640;    // layer-1 combined K: 512 (h) + 128 (emb, padded)
constexpr int K2 = 1024;   // layer-2 combined K: 512 (h2) + 512 (h1)
constexpr int S1 = 648;    // LDS row stride (elems), 4-bank lane stagger
constexpr int S2 = 1032;

__device__ __forceinline__ float sigmoidf_(float x) { return 1.f / (1.f + __expf(-x)); }

// out[n][k]: k<512 -> WH[k][n]; 512<=k<512+KXr -> WX[k-512][n]; else 0
__global__ void k_combine(const float* __restrict__ WH, const float* __restrict__ WX,
                          __bf16* __restrict__ out, int KXr, int Kp) {
  int idx = blockIdx.x * 256 + threadIdx.x;
  int total = 1536 * (Kp / 8);
  if (idx >= total) return;
  int n = idx % 1536;
  int kb = idx / 1536;
  bf16x8 v;
#pragma unroll
  for (int j = 0; j < 8; ++j) {
    int k = kb * 8 + j;
    float f = 0.f;
    if (k < 512) f = WH[(size_t)k * 1536 + n];
    else if (k - 512 < KXr) f = WX[(size_t)(k - 512) * 1536 + n];
    v[j] = (__bf16)f;
  }
  *(bf16x8*)(out + (size_t)n * Kp + kb * 8) = v;
}

__global__ void k_emb_pad(const float* __restrict__ in, __bf16* __restrict__ out) {
  int idx = blockIdx.x * 256 + threadIdx.x;
  if (idx >= 10000 * 128) return;
  int r = idx >> 7, c = idx & 127;
  out[idx] = (c < EMB) ? (__bf16)in[r * EMB + c] : (__bf16)0.f;
}

// two-counter sense barrier; leader thread only. Release/acquire fences around it
// give cross-XCD visibility (buffer_wbl2 on release, buffer_inv on acquire).
__device__ __forceinline__ void grid_bar(unsigned* cnt, unsigned* gen, int nblk) {
  __syncthreads();
  if (threadIdx.x == 0) {
    __threadfence();  // release: drain this XCD's L2 writes to LLC
    unsigned g = __hip_atomic_load(gen, __ATOMIC_RELAXED, __HIP_MEMORY_SCOPE_AGENT);
    unsigned a = __hip_atomic_fetch_add(cnt, 1u, __ATOMIC_RELAXED, __HIP_MEMORY_SCOPE_AGENT) + 1;
    if (a == (unsigned)nblk) {
      __hip_atomic_store(cnt, 0u, __ATOMIC_RELAXED, __HIP_MEMORY_SCOPE_AGENT);
      __hip_atomic_store(gen, g + 1, __ATOMIC_RELEASE, __HIP_MEMORY_SCOPE_AGENT);
    } else {
      while (__hip_atomic_load(gen, __ATOMIC_ACQUIRE, __HIP_MEMORY_SCOPE_AGENT) == g) {}
    }
    __threadfence();  // acquire: invalidate this CU/XCD's L1/L2
  }
  __syncthreads();
}

// Persistent pipelined 2-layer GRU. bid&4 ? layer-2 : layer-1 (XCD swizzle).
// Block tile: 256 rows x 48 gate-cols (16 units x {z,r,n}); weights LDS-resident
// for the whole sequence; f32 h state register-resident; bf16 h exchanged via global.
__global__ __launch_bounds__(512, 2)
void k_gru_persist(const int* __restrict__ tokens, const __bf16* __restrict__ embp,
                   const __bf16* __restrict__ W1c, const __bf16* __restrict__ W2c,
                   const float* __restrict__ b1, const float* __restrict__ b2,
                   __bf16* __restrict__ h1b0, __bf16* __restrict__ h1b1,
                   __bf16* __restrict__ h2b0, __bf16* __restrict__ h2b1,
                   const float* __restrict__ Wfc, const float* __restrict__ bfc,
                   float* __restrict__ out, unsigned* __restrict__ bar) {
  __shared__ __attribute__((aligned(16))) __bf16 wt[48 * S2];  // 99 KB

  const int bid = blockIdx.x, tid = threadIdx.x;
  const bool is2 = (bid & 4) != 0;
  const int lb = (bid >> 3) * 4 + (bid & 3);   // 0..127 within layer
  const int colg = lb & 31, rowg = lb >> 5;
  const int u0 = colg * 16, r0 = rowg * 256;

  // ---- stage this block's weight tile into LDS (once) ----
  if (is2) {
    int c = tid & 127, rb = tid >> 7;
#pragma unroll
    for (int i = 0; i < 12; ++i) {
      int row = i * 4 + rb;
      int col = (row >> 4) * U + u0 + (row & 15);
      *(bf16x8*)(wt + row * S2 + c * 8) = *(const bf16x8*)(W2c + (size_t)col * K2 + c * 8);
    }
  } else {
#pragma unroll
    for (int i = 0; i < 8; ++i) {
      int ch = i * 512 + tid;
      if (ch < 3840) {
        int row = ch / 80, c = ch % 80;
        int col = (row >> 4) * U + u0 + (row & 15);
        *(bf16x8*)(wt + row * S1 + c * 8) = *(const bf16x8*)(W1c + (size_t)col * K1 + c * 8);
      }
    }
  }
  __syncthreads();

  const int wv = tid >> 6, lane = tid & 63, ln = lane & 15, quad = lane >> 4;
  const int kq = quad * 8;
  const int rwA = r0 + wv * 32 + ln;

  // hoisted per-lane biases (unit u is loop-invariant)
  const float* bb = is2 ? b2 : b1;
  const int u = u0 + ln;
  const float bz  = bb[u] + bb[1536 + u];
  const float brr = bb[512 + u] + bb[1536 + 512 + u];
  const float bnx = bb[1024 + u];
  const float bnh = bb[1536 + 1024 + u];

  float hreg[2][4] = {{0.f, 0.f, 0.f, 0.f}, {0.f, 0.f, 0.f, 0.f}};  // f32 state, register-resident

#pragma unroll 1
  for (int s = 0; s <= SEQ; ++s) {
    const __bf16* h1r = (s & 1) ? h1b0 : h1b1;
    __bf16*       h1w = (s & 1) ? h1b1 : h1b0;
    const __bf16* h2r = (s & 1) ? h2b1 : h2b0;
    __bf16*       h2w = (s & 1) ? h2b0 : h2b1;
    const bool active = is2 ? (s >= 1) : (s < SEQ);

    if (active) {
      f32x4 az[2], ar[2], ax[2], ah[2];
      const f32x4 z4 = {0.f, 0.f, 0.f, 0.f};
#pragma unroll
      for (int j = 0; j < 2; ++j) { az[j] = z4; ar[j] = z4; ax[j] = z4; ah[j] = z4; }

      if (is2) {
#pragma unroll 4
        for (int ks = 0; ks < 16; ++ks) {
          int k = ks * 32 + kq;
          bf16x8 a0 = *(const bf16x8*)(h2r + (size_t)rwA * U + k);
          bf16x8 a1 = *(const bf16x8*)(h2r + (size_t)(rwA + 16) * U + k);
          bf16x8 bz_ = *(const bf16x8*)(wt + (0 + ln) * S2 + k);
          bf16x8 br_ = *(const bf16x8*)(wt + (16 + ln) * S2 + k);
          bf16x8 bn_ = *(const bf16x8*)(wt + (32 + ln) * S2 + k);
          az[0] = MFMA16(a0, bz_, az[0]); az[1] = MFMA16(a1, bz_, az[1]);
          ar[0] = MFMA16(a0, br_, ar[0]); ar[1] = MFMA16(a1, br_, ar[1]);
          ah[0] = MFMA16(a0, bn_, ah[0]); ah[1] = MFMA16(a1, bn_, ah[1]);
        }
#pragma unroll 4
        for (int ks = 0; ks < 16; ++ks) {
          int k = ks * 32 + kq;
          bf16x8 a0 = *(const bf16x8*)(h1r + (size_t)rwA * U + k);
          bf16x8 a1 = *(const bf16x8*)(h1r + (size_t)(rwA + 16) * U + k);
          bf16x8 bz_ = *(const bf16x8*)(wt + (0 + ln) * S2 + 512 + k);
          bf16x8 br_ = *(const bf16x8*)(wt + (16 + ln) * S2 + 512 + k);
          bf16x8 bn_ = *(const bf16x8*)(wt + (32 + ln) * S2 + 512 + k);
          az[0] = MFMA16(a0, bz_, az[0]); az[1] = MFMA16(a1, bz_, az[1]);
          ar[0] = MFMA16(a0, br_, ar[0]); ar[1] = MFMA16(a1, br_, ar[1]);
          ax[0] = MFMA16(a0, bn_, ax[0]); ax[1] = MFMA16(a1, bn_, ax[1]);
        }
      } else {
        int tok0 = tokens[(size_t)rwA * SEQ + s];
        int tok1 = tokens[(size_t)(rwA + 16) * SEQ + s];
#pragma unroll 4
        for (int ks = 0; ks < 16; ++ks) {
          int k = ks * 32 + kq;
          bf16x8 a0 = *(const bf16x8*)(h1r + (size_t)rwA * U + k);
          bf16x8 a1 = *(const bf16x8*)(h1r + (size_t)(rwA + 16) * U + k);
          bf16x8 bz_ = *(const bf16x8*)(wt + (0 + ln) * S1 + k);
          bf16x8 br_ = *(const bf16x8*)(wt + (16 + ln) * S1 + k);
          bf16x8 bn_ = *(const bf16x8*)(wt + (32 + ln) * S1 + k);
          az[0] = MFMA16(a0, bz_, az[0]); az[1] = MFMA16(a1, bz_, az[1]);
          ar[0] = MFMA16(a0, br_, ar[0]); ar[1] = MFMA16(a1, br_, ar[1]);
          ah[0] = MFMA16(a0, bn_, ah[0]); ah[1] = MFMA16(a1, bn_, ah[1]);
        }
#pragma unroll
        for (int ks = 0; ks < 4; ++ks) {
          int k = ks * 32 + kq;
          bf16x8 a0 = *(const bf16x8*)(embp + (size_t)tok0 * 128 + k);
          bf16x8 a1 = *(const bf16x8*)(embp + (size_t)tok1 * 128 + k);
          bf16x8 bz_ = *(const bf16x8*)(wt + (0 + ln) * S1 + 512 + k);
          bf16x8 br_ = *(const bf16x8*)(wt + (16 + ln) * S1 + 512 + k);
          bf16x8 bn_ = *(const bf16x8*)(wt + (32 + ln) * S1 + 512 + k);
          az[0] = MFMA16(a0, bz_, az[0]); az[1] = MFMA16(a1, bz_, az[1]);
          ar[0] = MFMA16(a0, br_, ar[0]); ar[1] = MFMA16(a1, br_, ar[1]);
          ax[0] = MFMA16(a0, bn_, ax[0]); ax[1] = MFMA16(a1, bn_, ax[1]);
        }
      }

      // gates + state update (C layout: col = ln, row = quad*4 + i)
      __bf16* hw = is2 ? h2w : h1w;
#pragma unroll
      for (int rt = 0; rt < 2; ++rt)
#pragma unroll
        for (int i = 0; i < 4; ++i) {
          int row = r0 + wv * 32 + rt * 16 + quad * 4 + i;
          float z = sigmoidf_(az[rt][i] + bz);
          float r = sigmoidf_(ar[rt][i] + brr);
          float hh = tanhf(ax[rt][i] + bnx + r * (ah[rt][i] + bnh));
          float hn = z * hreg[rt][i] + (1.f - z) * hh;
          hreg[rt][i] = hn;
          hw[(size_t)row * U + u] = (__bf16)hn;
        }
    }

    grid_bar(bar, bar + 64, gridDim.x);
  }

  // ---- FC epilogue: final h2 is in h2b1 (s=80 writes h2b[(80+1)&1]) ----
  if (bid < 64) {
    int r = bid * 16 + wv * 2 + (lane >> 5);
    int l32 = lane & 31;
    float sfc = 0.f;
#pragma unroll
    for (int k = l32; k < U; k += 32) sfc += (float)h2b1[(size_t)r * U + k] * Wfc[k];
#pragma unroll
    for (int off = 16; off; off >>= 1) sfc += __shfl_down(sfc, off, 32);
    if (l32 == 0) out[r] = sigmoidf_(sfc + bfc[0]);
  }
}

extern "C" void kernel_launch(void* const* d_in, const int* in_sizes, int n_in,
                              void* d_out, int out_size, void* d_ws, size_t ws_size,
                              hipStream_t stream) {
  const int*   tokens = (const int*)d_in[0];
  const float* emb = (const float*)d_in[1];
  const float* Wx1 = (const float*)d_in[2];
  const float* Wh1 = (const float*)d_in[3];
  const float* b1  = (const float*)d_in[4];
  const float* Wx2 = (const float*)d_in[5];
  const float* Wh2 = (const float*)d_in[6];
  const float* b2  = (const float*)d_in[7];
  const float* Wfc = (const float*)d_in[8];
  const float* bfc = (const float*)d_in[9];
  float* out = (float*)d_out;

  __bf16* W1c  = (__bf16*)d_ws;                 // [1536][640]
  __bf16* W2c  = W1c + 1536 * K1;               // [1536][1024]
  __bf16* embp = W2c + 1536 * K2;               // [10000][128]
  __bf16* h1b0 = embp + 10000 * 128;            // bf16 state double-buffers (1 MB each)
  __bf16* h1b1 = h1b0 + BATCH * U;
  __bf16* h2b0 = h1b1 + BATCH * U;
  __bf16* h2b1 = h2b0 + BATCH * U;
  unsigned* bar = (unsigned*)(h2b1 + BATCH * U); // [0]=cnt, [64]=gen (separate lines)

  k_combine<<<(1536 * (K1 / 8) + 255) / 256, 256, 0, stream>>>(Wh1, Wx1, W1c, EMB, K1);
  k_combine<<<(1536 * (K2 / 8) + 255) / 256, 256, 0, stream>>>(Wh2, Wx2, W2c, U, K2);
  k_emb_pad<<<(10000 * 128 + 255) / 256, 256, 0, stream>>>(emb, embp);

  // zero h state buffers (4 MB) + barrier counters (d_ws is poisoned 0xAA pre-call)
  hipMemsetAsync(h1b0, 0, (size_t)4 * BATCH * U * 2 + 512, stream);

  void* args[] = {(void*)&tokens, (void*)&embp, (void*)&W1c, (void*)&W2c,
                  (void*)&b1, (void*)&b2, (void*)&h1b0, (void*)&h1b1,
                  (void*)&h2b0, (void*)&h2b1, (void*)&Wfc, (void*)&bfc,
                  (void*)&out, (void*)&bar};
  hipLaunchCooperativeKernel((void*)k_gru_persist, dim3(256), dim3(512), args, 0, stream);
}

// Round 5
// 2670.737 us; speedup vs baseline: 1.1641x; 1.1641x over previous
//
#include <hip/hip_runtime.h>
#include <hip/hip_bf16.h>
#include <math.h>

typedef __bf16 bf16x8 __attribute__((ext_vector_type(8)));
typedef float f32x4 __attribute__((ext_vector_type(4)));

#define MFMA16(a,b,c) __builtin_amdgcn_mfma_f32_16x16x32_bf16(a,b,c,0,0,0)

constexpr int BATCH = 1024, SEQ = 80, EMB = 100, U = 512;
constexpr int K1 = 640;    // layer-1 combined K: 512 (h) + 128 (emb, padded)
constexpr int K2 = 1024;   // layer-2 combined K: 512 (h2) + 512 (h1)
constexpr int S1 = 648;    // LDS row stride (elems), 2-way bank alias only (free)
constexpr int S2 = 1032;

__device__ __forceinline__ float sigmoidf_(float x) { return 1.f / (1.f + __expf(-x)); }

// out[n][k]: k<512 -> WH[k][n]; 512<=k<512+KXr -> WX[k-512][n]; else 0
__global__ void k_combine(const float* __restrict__ WH, const float* __restrict__ WX,
                          __bf16* __restrict__ out, int KXr, int Kp) {
  int idx = blockIdx.x * 256 + threadIdx.x;
  int total = 1536 * (Kp / 8);
  if (idx >= total) return;
  int n = idx % 1536;
  int kb = idx / 1536;
  bf16x8 v;
#pragma unroll
  for (int j = 0; j < 8; ++j) {
    int k = kb * 8 + j;
    float f = 0.f;
    if (k < 512) f = WH[(size_t)k * 1536 + n];
    else if (k - 512 < KXr) f = WX[(size_t)(k - 512) * 1536 + n];
    v[j] = (__bf16)f;
  }
  *(bf16x8*)(out + (size_t)n * Kp + kb * 8) = v;
}

__global__ void k_emb_pad(const float* __restrict__ in, __bf16* __restrict__ out) {
  int idx = blockIdx.x * 256 + threadIdx.x;
  if (idx >= 10000 * 128) return;
  int r = idx >> 7, c = idx & 127;
  out[idx] = (c < EMB) ? (__bf16)in[r * EMB + c] : (__bf16)0.f;
}

// Monotone-counter grid barrier. Poll = relaxed fetch_add(0): RMWs execute at the
// coherence point (fresh value, NO per-poll buffer_inv). One release fence (wbl2)
// before arrive, one acquire fence (inv) after exit — not per poll iteration.
__device__ __forceinline__ void grid_bar(unsigned* cnt, int nblk) {
  __syncthreads();
  if (threadIdx.x == 0) {
    __builtin_amdgcn_fence(__ATOMIC_RELEASE, "agent");   // drain + wbl2: publish h writes
    unsigned a = __hip_atomic_fetch_add(cnt, 1u, __ATOMIC_RELAXED, __HIP_MEMORY_SCOPE_AGENT);
    unsigned target = (a / (unsigned)nblk + 1u) * (unsigned)nblk;
    while (__hip_atomic_fetch_add(cnt, 0u, __ATOMIC_RELAXED, __HIP_MEMORY_SCOPE_AGENT) < target)
      __builtin_amdgcn_s_sleep(4);
    __builtin_amdgcn_fence(__ATOMIC_ACQUIRE, "agent");   // single inv: see others' h
  }
  __syncthreads();
}

// Persistent pipelined 2-layer GRU. bid&4 ? layer-2 : layer-1 (XCD swizzle).
// Block tile: 256 rows x 48 gate-cols (16 units x {z,r,n}); weights LDS-resident;
// f32 h register-resident; bf16 h exchanged via global in k-blocked layout
// h[kb][row][8] (kb = unit/8) so A-fragment loads are 256B-contiguous per quad.
__global__ __launch_bounds__(512, 2)
void k_gru_persist(const int* __restrict__ tokens, const __bf16* __restrict__ embp,
                   const __bf16* __restrict__ W1c, const __bf16* __restrict__ W2c,
                   const float* __restrict__ b1, const float* __restrict__ b2,
                   __bf16* __restrict__ h1b0, __bf16* __restrict__ h1b1,
                   __bf16* __restrict__ h2b0, __bf16* __restrict__ h2b1,
                   const float* __restrict__ Wfc, const float* __restrict__ bfc,
                   float* __restrict__ out, unsigned* __restrict__ bar) {
  __shared__ __attribute__((aligned(16))) __bf16 wt[48 * S2];  // 99 KB

  const int bid = blockIdx.x, tid = threadIdx.x;
  const bool is2 = (bid & 4) != 0;
  const int lb = (bid >> 3) * 4 + (bid & 3);   // 0..127 within layer
  const int colg = lb & 31, rowg = lb >> 5;
  const int u0 = colg * 16, r0 = rowg * 256;

  // ---- stage this block's weight tile into LDS (once) ----
  if (is2) {
    int c = tid & 127, rb = tid >> 7;
#pragma unroll
    for (int i = 0; i < 12; ++i) {
      int row = i * 4 + rb;
      int col = (row >> 4) * U + u0 + (row & 15);
      *(bf16x8*)(wt + row * S2 + c * 8) = *(const bf16x8*)(W2c + (size_t)col * K2 + c * 8);
    }
  } else {
#pragma unroll
    for (int i = 0; i < 8; ++i) {
      int ch = i * 512 + tid;
      if (ch < 3840) {
        int row = ch / 80, c = ch % 80;
        int col = (row >> 4) * U + u0 + (row & 15);
        *(bf16x8*)(wt + row * S1 + c * 8) = *(const bf16x8*)(W1c + (size_t)col * K1 + c * 8);
      }
    }
  }
  __syncthreads();

  const int wv = tid >> 6, lane = tid & 63, ln = lane & 15, quad = lane >> 4;
  const int kq = quad * 8;
  const int rwA = r0 + wv * 32 + ln;

  const float* bb = is2 ? b2 : b1;
  const int u = u0 + ln;
  const float bz  = bb[u] + bb[1536 + u];
  const float brr = bb[512 + u] + bb[1536 + 512 + u];
  const float bnx = bb[1024 + u];
  const float bnh = bb[1536 + 1024 + u];
  const size_t wbase = ((size_t)(u >> 3) * 1024) * 8 + (u & 7);  // k-blocked write base

  float hreg[2][4] = {{0.f, 0.f, 0.f, 0.f}, {0.f, 0.f, 0.f, 0.f}};

#pragma unroll 1
  for (int s = 0; s <= SEQ; ++s) {
    const __bf16* h1r = (s & 1) ? h1b0 : h1b1;
    __bf16*       h1w = (s & 1) ? h1b1 : h1b0;
    const __bf16* h2r = (s & 1) ? h2b1 : h2b0;
    __bf16*       h2w = (s & 1) ? h2b0 : h2b1;
    const bool active = is2 ? (s >= 1) : (s < SEQ);

    if (active) {
      f32x4 az[2], ar[2], ax[2], ah[2];
      const f32x4 z4 = {0.f, 0.f, 0.f, 0.f};
#pragma unroll
      for (int j = 0; j < 2; ++j) { az[j] = z4; ar[j] = z4; ax[j] = z4; ah[j] = z4; }

      if (is2) {
#pragma unroll 8
        for (int ks = 0; ks < 16; ++ks) {
          int k = ks * 32 + kq;
          const __bf16* ab = h2r + ((size_t)(ks * 4 + quad) * 1024 + rwA) * 8;
          bf16x8 a0 = *(const bf16x8*)(ab);
          bf16x8 a1 = *(const bf16x8*)(ab + 128);
          bf16x8 bz_ = *(const bf16x8*)(wt + (0 + ln) * S2 + k);
          bf16x8 br_ = *(const bf16x8*)(wt + (16 + ln) * S2 + k);
          bf16x8 bn_ = *(const bf16x8*)(wt + (32 + ln) * S2 + k);
          az[0] = MFMA16(a0, bz_, az[0]); az[1] = MFMA16(a1, bz_, az[1]);
          ar[0] = MFMA16(a0, br_, ar[0]); ar[1] = MFMA16(a1, br_, ar[1]);
          ah[0] = MFMA16(a0, bn_, ah[0]); ah[1] = MFMA16(a1, bn_, ah[1]);
        }
#pragma unroll 8
        for (int ks = 0; ks < 16; ++ks) {
          int k = ks * 32 + kq;
          const __bf16* ab = h1r + ((size_t)(ks * 4 + quad) * 1024 + rwA) * 8;
          bf16x8 a0 = *(const bf16x8*)(ab);
          bf16x8 a1 = *(const bf16x8*)(ab + 128);
          bf16x8 bz_ = *(const bf16x8*)(wt + (0 + ln) * S2 + 512 + k);
          bf16x8 br_ = *(const bf16x8*)(wt + (16 + ln) * S2 + 512 + k);
          bf16x8 bn_ = *(const bf16x8*)(wt + (32 + ln) * S2 + 512 + k);
          az[0] = MFMA16(a0, bz_, az[0]); az[1] = MFMA16(a1, bz_, az[1]);
          ar[0] = MFMA16(a0, br_, ar[0]); ar[1] = MFMA16(a1, br_, ar[1]);
          ax[0] = MFMA16(a0, bn_, ax[0]); ax[1] = MFMA16(a1, bn_, ax[1]);
        }
      } else {
        int tok0 = tokens[(size_t)rwA * SEQ + s];
        int tok1 = tokens[(size_t)(rwA + 16) * SEQ + s];
#pragma unroll 8
        for (int ks = 0; ks < 16; ++ks) {
          int k = ks * 32 + kq;
          const __bf16* ab = h1r + ((size_t)(ks * 4 + quad) * 1024 + rwA) * 8;
          bf16x8 a0 = *(const bf16x8*)(ab);
          bf16x8 a1 = *(const bf16x8*)(ab + 128);
          bf16x8 bz_ = *(const bf16x8*)(wt + (0 + ln) * S1 + k);
          bf16x8 br_ = *(const bf16x8*)(wt + (16 + ln) * S1 + k);
          bf16x8 bn_ = *(const bf16x8*)(wt + (32 + ln) * S1 + k);
          az[0] = MFMA16(a0, bz_, az[0]); az[1] = MFMA16(a1, bz_, az[1]);
          ar[0] = MFMA16(a0, br_, ar[0]); ar[1] = MFMA16(a1, br_, ar[1]);
          ah[0] = MFMA16(a0, bn_, ah[0]); ah[1] = MFMA16(a1, bn_, ah[1]);
        }
#pragma unroll
        for (int ks = 0; ks < 4; ++ks) {
          int k = ks * 32 + kq;
          bf16x8 a0 = *(const bf16x8*)(embp + (size_t)tok0 * 128 + k);
          bf16x8 a1 = *(const bf16x8*)(embp + (size_t)tok1 * 128 + k);
          bf16x8 bz_ = *(const bf16x8*)(wt + (0 + ln) * S1 + 512 + k);
          bf16x8 br_ = *(const bf16x8*)(wt + (16 + ln) * S1 + 512 + k);
          bf16x8 bn_ = *(const bf16x8*)(wt + (32 + ln) * S1 + 512 + k);
          az[0] = MFMA16(a0, bz_, az[0]); az[1] = MFMA16(a1, bz_, az[1]);
          ar[0] = MFMA16(a0, br_, ar[0]); ar[1] = MFMA16(a1, br_, ar[1]);
          ax[0] = MFMA16(a0, bn_, ax[0]); ax[1] = MFMA16(a1, bn_, ax[1]);
        }
      }

      // gates + state update (C layout: col = ln -> unit, row = quad*4 + i)
      __bf16* hw = is2 ? h2w : h1w;
#pragma unroll
      for (int rt = 0; rt < 2; ++rt)
#pragma unroll
        for (int i = 0; i < 4; ++i) {
          int row = r0 + wv * 32 + rt * 16 + quad * 4 + i;
          float z = sigmoidf_(az[rt][i] + bz);
          float r = sigmoidf_(ar[rt][i] + brr);
          float hh = tanhf(ax[rt][i] + bnx + r * (ah[rt][i] + bnh));
          float hn = z * hreg[rt][i] + (1.f - z) * hh;
          hreg[rt][i] = hn;
          hw[wbase + (size_t)row * 8] = (__bf16)hn;
        }
    }

    grid_bar(bar, gridDim.x);
  }

  // ---- FC epilogue: final h2 in h2b1 (k-blocked layout) ----
  if (bid < 64) {
    int r = bid * 16 + wv * 2 + (lane >> 5);
    int l32 = lane & 31;
    float sfc = 0.f;
#pragma unroll
    for (int k = l32; k < U; k += 32)
      sfc += (float)h2b1[((size_t)(k >> 3) * 1024 + r) * 8 + (k & 7)] * Wfc[k];
#pragma unroll
    for (int off = 16; off; off >>= 1) sfc += __shfl_down(sfc, off, 32);
    if (l32 == 0) out[r] = sigmoidf_(sfc + bfc[0]);
  }
}

extern "C" void kernel_launch(void* const* d_in, const int* in_sizes, int n_in,
                              void* d_out, int out_size, void* d_ws, size_t ws_size,
                              hipStream_t stream) {
  const int*   tokens = (const int*)d_in[0];
  const float* emb = (const float*)d_in[1];
  const float* Wx1 = (const float*)d_in[2];
  const float* Wh1 = (const float*)d_in[3];
  const float* b1  = (const float*)d_in[4];
  const float* Wx2 = (const float*)d_in[5];
  const float* Wh2 = (const float*)d_in[6];
  const float* b2  = (const float*)d_in[7];
  const float* Wfc = (const float*)d_in[8];
  const float* bfc = (const float*)d_in[9];
  float* out = (float*)d_out;

  __bf16* W1c  = (__bf16*)d_ws;                 // [1536][640]
  __bf16* W2c  = W1c + 1536 * K1;               // [1536][1024]
  __bf16* embp = W2c + 1536 * K2;               // [10000][128]
  __bf16* h1b0 = embp + 10000 * 128;            // bf16 states, k-blocked [64][1024][8]
  __bf16* h1b1 = h1b0 + BATCH * U;
  __bf16* h2b0 = h1b1 + BATCH * U;
  __bf16* h2b1 = h2b0 + BATCH * U;
  unsigned* bar = (unsigned*)(h2b1 + BATCH * U); // monotone arrival counter

  k_combine<<<(1536 * (K1 / 8) + 255) / 256, 256, 0, stream>>>(Wh1, Wx1, W1c, EMB, K1);
  k_combine<<<(1536 * (K2 / 8) + 255) / 256, 256, 0, stream>>>(Wh2, Wx2, W2c, U, K2);
  k_emb_pad<<<(10000 * 128 + 255) / 256, 256, 0, stream>>>(emb, embp);

  // zero h state buffers (4 MB) + barrier counter (d_ws is poisoned 0xAA pre-call)
  hipMemsetAsync(h1b0, 0, (size_t)4 * BATCH * U * 2 + 512, stream);

  void* args[] = {(void*)&tokens, (void*)&embp, (void*)&W1c, (void*)&W2c,
                  (void*)&b1, (void*)&b2, (void*)&h1b0, (void*)&h1b1,
                  (void*)&h2b0, (void*)&h2b1, (void*)&Wfc, (void*)&bfc,
                  (void*)&out, (void*)&bar};
  hipLaunchCooperativeKernel((void*)k_gru_persist, dim3(256), dim3(512), args, 0, stream);
}

// Round 6
// 1413.644 us; speedup vs baseline: 2.1994x; 1.8893x over previous
//
#include <hip/hip_runtime.h>
#include <hip/hip_bf16.h>
#include <math.h>

typedef __bf16 bf16x8 __attribute__((ext_vector_type(8)));
typedef float f32x4 __attribute__((ext_vector_type(4)));

#define MFMA16(a,b,c) __builtin_amdgcn_mfma_f32_16x16x32_bf16(a,b,c,0,0,0)

constexpr int BATCH = 1024, SEQ = 80, EMB = 100, U = 512;
constexpr int K1 = 640;    // layer-1 combined K: 512 (h1) + 128 (emb, padded)
constexpr int K2 = 1024;   // layer-2 combined K: 512 (h2) + 512 (h1)
constexpr int S1 = 648;    // LDS stride: 1296B = 324 dw == 4 mod 32 -> 2-way only (free)
constexpr int S2 = 1032;   // 2064B = 516 dw == 4 mod 32 -> 2-way only (free)

__device__ __forceinline__ float sigmoidf_(float x) { return 1.f / (1.f + __expf(-x)); }

// out[n][k]: k<512 -> WH[k][n]; 512<=k<512+KXr -> WX[k-512][n]; else 0
__global__ void k_combine(const float* __restrict__ WH, const float* __restrict__ WX,
                          __bf16* __restrict__ out, int KXr, int Kp) {
  int idx = blockIdx.x * 256 + threadIdx.x;
  int total = 1536 * (Kp / 8);
  if (idx >= total) return;
  int n = idx % 1536;
  int kb = idx / 1536;
  bf16x8 v;
#pragma unroll
  for (int j = 0; j < 8; ++j) {
    int k = kb * 8 + j;
    float f = 0.f;
    if (k < 512) f = WH[(size_t)k * 1536 + n];
    else if (k - 512 < KXr) f = WX[(size_t)(k - 512) * 1536 + n];
    v[j] = (__bf16)f;
  }
  *(bf16x8*)(out + (size_t)n * Kp + kb * 8) = v;
}

__global__ void k_emb_pad(const float* __restrict__ in, __bf16* __restrict__ out) {
  int idx = blockIdx.x * 256 + threadIdx.x;
  if (idx >= 10000 * 128) return;
  int r = idx >> 7, c = idx & 127;
  out[idx] = (c < EMB) ? (__bf16)in[r * EMB + c] : (__bf16)0.f;
}

// Group-local (32-block) monotone barrier. Poll = relaxed fetch_add(0) (fresh at
// coherence point, no per-poll inv). One release fence before arrive, one acquire
// fence after exit. Groups are independent -> no global skew coupling.
__device__ __forceinline__ void group_bar(unsigned* cnt) {
  __syncthreads();
  if (threadIdx.x == 0) {
    __builtin_amdgcn_fence(__ATOMIC_RELEASE, "agent");
    unsigned a = __hip_atomic_fetch_add(cnt, 1u, __ATOMIC_RELAXED, __HIP_MEMORY_SCOPE_AGENT);
    unsigned target = (a / 32u + 1u) * 32u;
    while (__hip_atomic_fetch_add(cnt, 0u, __ATOMIC_RELAXED, __HIP_MEMORY_SCOPE_AGENT) < target)
      __builtin_amdgcn_s_sleep(1);
    __builtin_amdgcn_fence(__ATOMIC_ACQUIRE, "agent");
  }
  __syncthreads();
}

// Persistent fused 2-layer GRU, 8 independent row-groups of 32 blocks.
// Group g (bid&7, XCD-aligned under round-robin) owns rows [g*128,(g+1)*128).
// Block lb (bid>>3) owns units [lb*16, lb*16+16) for BOTH layers (diagonal pipeline:
// layer-1 @ t=s, layer-2 @ t=s-1). Both weight tiles LDS-resident (157 KB).
// h1 A-fragment loaded once, feeds layer-1 h-part AND layer-2 x-part (6 MFMAs/load).
__global__ __launch_bounds__(512, 1)
void k_gru_persist(const int* __restrict__ tokens, const __bf16* __restrict__ embp,
                   const __bf16* __restrict__ W1c, const __bf16* __restrict__ W2c,
                   const float* __restrict__ b1, const float* __restrict__ b2,
                   __bf16* __restrict__ h1b0, __bf16* __restrict__ h1b1,
                   __bf16* __restrict__ h2b0, __bf16* __restrict__ h2b1,
                   const float* __restrict__ Wfc, const float* __restrict__ bfc,
                   float* __restrict__ out, unsigned* __restrict__ bar) {
  __shared__ __attribute__((aligned(16))) __bf16 wt1[48 * S1];  // 62 KB
  __shared__ __attribute__((aligned(16))) __bf16 wt2[48 * S2];  // 99 KB

  const int bid = blockIdx.x, tid = threadIdx.x;
  const int g = bid & 7, lb = bid >> 3;
  const int u0 = lb * 16, r0 = g * 128;

  // ---- stage both weight tiles into LDS (once) ----
#pragma unroll
  for (int i = 0; i < 8; ++i) {                 // wt1: 48 rows x 80 chunks
    int ch = i * 512 + tid;
    if (ch < 3840) {
      int row = ch / 80, c = ch % 80;
      int col = (row >> 4) * U + u0 + (row & 15);
      *(bf16x8*)(wt1 + row * S1 + c * 8) = *(const bf16x8*)(W1c + (size_t)col * K1 + c * 8);
    }
  }
#pragma unroll
  for (int i = 0; i < 12; ++i) {                // wt2: 48 rows x 128 chunks
    int ch = i * 512 + tid;
    int row = ch >> 7, c = ch & 127;
    int col = (row >> 4) * U + u0 + (row & 15);
    *(bf16x8*)(wt2 + row * S2 + c * 8) = *(const bf16x8*)(W2c + (size_t)col * K2 + c * 8);
  }
  __syncthreads();

  const int wv = tid >> 6, lane = tid & 63, ln = lane & 15, quad = lane >> 4;
  const int kq = quad * 8;
  const int rw0 = r0 + wv * 16;      // this wave's 16-row tile
  const int rwA = rw0 + ln;          // A-operand row for lane

  const int u = u0 + ln;
  const float bz1  = b1[u] + b1[1536 + u];
  const float br1  = b1[512 + u] + b1[1536 + 512 + u];
  const float bn1x = b1[1024 + u];
  const float bn1h = b1[1536 + 1024 + u];
  const float bz2  = b2[u] + b2[1536 + u];
  const float br2  = b2[512 + u] + b2[1536 + 512 + u];
  const float bn2x = b2[1024 + u];
  const float bn2h = b2[1536 + 1024 + u];
  const size_t wbase = ((size_t)(u >> 3) * 1024) * 8 + (u & 7);  // k-blocked write base

  float h1st[4] = {0.f, 0.f, 0.f, 0.f};
  float h2st[4] = {0.f, 0.f, 0.f, 0.f};
  unsigned* cnt = bar + g * 64;      // 256B-spaced per-group counter

#pragma unroll 1
  for (int s = 0; s <= SEQ; ++s) {
    const __bf16* h1r = (s & 1) ? h1b0 : h1b1;
    __bf16*       h1w = (s & 1) ? h1b1 : h1b0;
    const __bf16* h2r = (s & 1) ? h2b1 : h2b0;
    __bf16*       h2w = (s & 1) ? h2b0 : h2b1;

    f32x4 z1, r1, n1h, n1x, z2, r2, n2h, n2x;
    z1 = r1 = n1h = n1x = z2 = r2 = n2h = n2x = (f32x4){0.f, 0.f, 0.f, 0.f};

    // ---- shared h1 pass: layer-1 h-part + layer-2 x-part (one A-load, 6 MFMAs) ----
#pragma unroll 8
    for (int ks = 0; ks < 16; ++ks) {
      int k = ks * 32 + kq;
      bf16x8 a = *(const bf16x8*)(h1r + ((size_t)(ks * 4 + quad) * 1024 + rwA) * 8);
      z1  = MFMA16(a, *(const bf16x8*)(wt1 + (0 + ln) * S1 + k), z1);
      r1  = MFMA16(a, *(const bf16x8*)(wt1 + (16 + ln) * S1 + k), r1);
      n1h = MFMA16(a, *(const bf16x8*)(wt1 + (32 + ln) * S1 + k), n1h);
      z2  = MFMA16(a, *(const bf16x8*)(wt2 + (0 + ln) * S2 + 512 + k), z2);
      r2  = MFMA16(a, *(const bf16x8*)(wt2 + (16 + ln) * S2 + 512 + k), r2);
      n2x = MFMA16(a, *(const bf16x8*)(wt2 + (32 + ln) * S2 + 512 + k), n2x);
    }
    // ---- layer-2 h-part (h2 recurrence) ----
#pragma unroll 8
    for (int ks = 0; ks < 16; ++ks) {
      int k = ks * 32 + kq;
      bf16x8 a = *(const bf16x8*)(h2r + ((size_t)(ks * 4 + quad) * 1024 + rwA) * 8);
      z2  = MFMA16(a, *(const bf16x8*)(wt2 + (0 + ln) * S2 + k), z2);
      r2  = MFMA16(a, *(const bf16x8*)(wt2 + (16 + ln) * S2 + k), r2);
      n2h = MFMA16(a, *(const bf16x8*)(wt2 + (32 + ln) * S2 + k), n2h);
    }
    // ---- layer-1 x-part (embedding) ----
    {
      int se = (s < SEQ) ? s : SEQ - 1;
      int tok = tokens[(size_t)rwA * SEQ + se];
#pragma unroll
      for (int ks = 0; ks < 4; ++ks) {
        int k = ks * 32 + kq;
        bf16x8 a = *(const bf16x8*)(embp + (size_t)tok * 128 + k);
        z1  = MFMA16(a, *(const bf16x8*)(wt1 + (0 + ln) * S1 + 512 + k), z1);
        r1  = MFMA16(a, *(const bf16x8*)(wt1 + (16 + ln) * S1 + 512 + k), r1);
        n1x = MFMA16(a, *(const bf16x8*)(wt1 + (32 + ln) * S1 + 512 + k), n1x);
      }
    }

    // ---- gate updates (C layout: col = ln -> unit, row = quad*4 + i) ----
    if (s < SEQ) {
#pragma unroll
      for (int i = 0; i < 4; ++i) {
        int row = rw0 + quad * 4 + i;
        float z = sigmoidf_(z1[i] + bz1);
        float r = sigmoidf_(r1[i] + br1);
        float hh = tanhf(n1x[i] + bn1x + r * (n1h[i] + bn1h));
        float hn = z * h1st[i] + (1.f - z) * hh;
        h1st[i] = hn;
        h1w[wbase + (size_t)row * 8] = (__bf16)hn;
      }
    }
    if (s >= 1) {
#pragma unroll
      for (int i = 0; i < 4; ++i) {
        int row = rw0 + quad * 4 + i;
        float z = sigmoidf_(z2[i] + bz2);
        float r = sigmoidf_(r2[i] + br2);
        float hh = tanhf(n2x[i] + bn2x + r * (n2h[i] + bn2h));
        float hn = z * h2st[i] + (1.f - z) * hh;
        h2st[i] = hn;
        h2w[wbase + (size_t)row * 8] = (__bf16)hn;
      }
    }

    group_bar(cnt);
  }

  // ---- FC epilogue: final h2 in h2b1 (k-blocked). 8 blocks/group x 16 rows ----
  if (lb < 8) {
    int row = r0 + lb * 16 + wv * 2 + (lane >> 5);
    int l32 = lane & 31;
    float sfc = 0.f;
#pragma unroll
    for (int k = l32; k < U; k += 32)
      sfc += (float)h2b1[((size_t)(k >> 3) * 1024 + row) * 8 + (k & 7)] * Wfc[k];
#pragma unroll
    for (int off = 16; off; off >>= 1) sfc += __shfl_down(sfc, off, 32);
    if (l32 == 0) out[row] = sigmoidf_(sfc + bfc[0]);
  }
}

extern "C" void kernel_launch(void* const* d_in, const int* in_sizes, int n_in,
                              void* d_out, int out_size, void* d_ws, size_t ws_size,
                              hipStream_t stream) {
  const int*   tokens = (const int*)d_in[0];
  const float* emb = (const float*)d_in[1];
  const float* Wx1 = (const float*)d_in[2];
  const float* Wh1 = (const float*)d_in[3];
  const float* b1  = (const float*)d_in[4];
  const float* Wx2 = (const float*)d_in[5];
  const float* Wh2 = (const float*)d_in[6];
  const float* b2  = (const float*)d_in[7];
  const float* Wfc = (const float*)d_in[8];
  const float* bfc = (const float*)d_in[9];
  float* out = (float*)d_out;

  __bf16* W1c  = (__bf16*)d_ws;                 // [1536][640]
  __bf16* W2c  = W1c + 1536 * K1;               // [1536][1024]
  __bf16* embp = W2c + 1536 * K2;               // [10000][128]
  __bf16* h1b0 = embp + 10000 * 128;            // bf16 states, k-blocked [64][1024][8]
  __bf16* h1b1 = h1b0 + BATCH * U;
  __bf16* h2b0 = h1b1 + BATCH * U;
  __bf16* h2b1 = h2b0 + BATCH * U;
  unsigned* bar = (unsigned*)(h2b1 + BATCH * U); // 8 per-group counters, 256B apart

  k_combine<<<(1536 * (K1 / 8) + 255) / 256, 256, 0, stream>>>(Wh1, Wx1, W1c, EMB, K1);
  k_combine<<<(1536 * (K2 / 8) + 255) / 256, 256, 0, stream>>>(Wh2, Wx2, W2c, U, K2);
  k_emb_pad<<<(10000 * 128 + 255) / 256, 256, 0, stream>>>(emb, embp);

  // zero h state buffers (4 MB) + barrier counters
  hipMemsetAsync(h1b0, 0, (size_t)4 * BATCH * U * 2 + 2048, stream);

  void* args[] = {(void*)&tokens, (void*)&embp, (void*)&W1c, (void*)&W2c,
                  (void*)&b1, (void*)&b2, (void*)&h1b0, (void*)&h1b1,
                  (void*)&h2b0, (void*)&h2b1, (void*)&Wfc, (void*)&bfc,
                  (void*)&out, (void*)&bar};
  hipLaunchCooperativeKernel((void*)k_gru_persist, dim3(256), dim3(512), args, 0, stream);
}